// Round 4
// baseline (125.317 us; speedup 1.0000x reference)
//
#include <hip/hip_runtime.h>

#define TPB 256
#define BATCH 262144
#define HST 40      // fp16 h/h2 LDS row stride in halves (80B rows: 16B-aligned b128 reads, <=2-way banks)
#define EST 10      // e-transpose row stride in floats (40B rows)
#define HREG 1280   // h/h2 region size in dwords (64 rows * 40 halves / 2)
#define SLICE 1920  // per-wave LDS dwords: h/h2 [0,1280) + e [1280,1920)

typedef __fp16   fp16x2  __attribute__((ext_vector_type(2)));   // cvt_pkrtz result type
typedef _Float16 half8_t __attribute__((ext_vector_type(8)));
typedef float    f32x4   __attribute__((ext_vector_type(4)));   // native vector: ok for nontemporal builtins

// Intra-wave LDS fence: waits for this wave's DS ops; LDS slices are
// per-wave so no block-wide __syncthreads is needed.
#define WAVE_LDS_FENCE() asm volatile("s_waitcnt lgkmcnt(0)" ::: "memory")

__device__ __forceinline__ float fast_tanh(float x) {
    float ax = fabsf(x);
    float e  = __expf(-2.0f * ax);
    float t  = (1.0f - e) * __builtin_amdgcn_rcpf(1.0f + e);
    return copysignf(t, x);
}

// uniform float -> SGPR hint
__device__ __forceinline__ float to_sgpr(float v) {
    return __builtin_bit_cast(float, __builtin_amdgcn_readfirstlane(__builtin_bit_cast(int, v)));
}

template <int MASK>
__device__ __forceinline__ void ry_gate(float* psi, float c, float s) {
#pragma unroll
    for (int i = 0; i < 16; i++) {
        if (!(i & MASK)) {
            float a = psi[i], b = psi[i | MASK];
            psi[i]        = c * a - s * b;
            psi[i | MASK] = s * a + c * b;
        }
    }
}

template <int CM, int TM>
__device__ __forceinline__ void cnot_gate(float* psi) {
#pragma unroll
    for (int i = 0; i < 16; i++) {
        if ((i & CM) && !(i & TM)) {
            float t = psi[i];
            psi[i] = psi[i | TM];
            psi[i | TM] = t;
        }
    }
}

// RTZ pack f32x8 -> f16x8 (MFMA fragment)
__device__ __forceinline__ half8_t cvt8(f32x4 a, f32x4 b) {
    fp16x2 p0 = __builtin_amdgcn_cvt_pkrtz(a[0], a[1]);
    fp16x2 p1 = __builtin_amdgcn_cvt_pkrtz(a[2], a[3]);
    fp16x2 p2 = __builtin_amdgcn_cvt_pkrtz(b[0], b[1]);
    fp16x2 p3 = __builtin_amdgcn_cvt_pkrtz(b[2], b[3]);
    half8_t r;
    r[0] = (_Float16)p0[0]; r[1] = (_Float16)p0[1];
    r[2] = (_Float16)p1[0]; r[3] = (_Float16)p1[1];
    r[4] = (_Float16)p2[0]; r[5] = (_Float16)p2[1];
    r[6] = (_Float16)p3[0]; r[7] = (_Float16)p3[1];
    return r;
}

__global__ __launch_bounds__(TPB, 4) void qnet_kernel(
    const float* __restrict__ state,
    const float* __restrict__ W1, const float* __restrict__ b1,
    const float* __restrict__ W2, const float* __restrict__ b2,
    const float* __restrict__ qp,
    const float* __restrict__ H1, const float* __restrict__ c1,
    const float* __restrict__ H2, const float* __restrict__ c2,
    float* __restrict__ out)
{
    __shared__ float sh[4 * SLICE];

    const int tid  = threadIdx.x;
    const int lane = tid & 63;
    const int wv   = tid >> 6;
    const int l15  = lane & 15;
    const int lq   = lane >> 4;
    const int rowBase = blockIdx.x * TPB + wv * 64;
    float*  hb   = sh + wv * SLICE;
    __fp16* hb16 = reinterpret_cast<__fp16*>(hb);
    float*  eb   = hb + HREG;

    // ---- issue kt=0 state loads (32 VGPR in flight) ----
    f32x4 xa0[4], xb0[4];
#pragma unroll
    for (int mt = 0; mt < 4; mt++) {
        const float* p0 = state + (size_t)(rowBase + 16 * mt + l15) * 64 + lq * 8;
        xa0[mt] = __builtin_nontemporal_load(reinterpret_cast<const f32x4*>(p0));
        xb0[mt] = __builtin_nontemporal_load(reinterpret_cast<const f32x4*>(p0 + 4));
    }

    // ---- issue W1 / W2 / H2 weight loads + per-lane biases (latency overlap) ----
    f32x4 w1a[2][2], w1b[2][2];
#pragma unroll
    for (int u = 0; u < 2; u++)
#pragma unroll
        for (int kt = 0; kt < 2; kt++) {
            const float* p = W1 + (16 * u + l15) * 64 + 32 * kt + lq * 8;
            w1a[u][kt] = *reinterpret_cast<const f32x4*>(p);
            w1b[u][kt] = *reinterpret_cast<const f32x4*>(p + 4);
        }
    f32x4 w2a, w2b, h2wa, h2wb;
    {
        const float* p = W2 + (l15 & 3) * 32 + lq * 8;
        w2a = *reinterpret_cast<const f32x4*>(p);
        w2b = *reinterpret_cast<const f32x4*>(p + 4);
        const float* q = H2 + l15 * 32 + lq * 8;
        h2wa = *reinterpret_cast<const f32x4*>(q);
        h2wb = *reinterpret_cast<const f32x4*>(q + 4);
    }
    const float bias0 = b1[l15];
    const float bias1 = b1[16 + l15];
    const float cc    = c2[l15];

    // ---- uniform qp sincos in the load shadow, pinned to SGPRs ----
    float qpc[8], qps[8];
#pragma unroll
    for (int g = 0; g < 8; g++) {
        float sg, cg;
        __sincosf(0.5f * qp[g], &sg, &cg);
        qps[g] = to_sgpr(sg);
        qpc[g] = to_sgpr(cg);
    }

    // ---- cvt kt0 A-frags (frees 32 f32 regs), then issue kt=1 loads ----
    half8_t aft[4];
#pragma unroll
    for (int mt = 0; mt < 4; mt++) aft[mt] = cvt8(xa0[mt], xb0[mt]);

    f32x4 xa1[4], xb1[4];
#pragma unroll
    for (int mt = 0; mt < 4; mt++) {
        const float* p0 = state + (size_t)(rowBase + 16 * mt + l15) * 64 + 32 + lq * 8;
        xa1[mt] = __builtin_nontemporal_load(reinterpret_cast<const f32x4*>(p0));
        xb1[mt] = __builtin_nontemporal_load(reinterpret_cast<const f32x4*>(p0 + 4));
    }

    // ---- cvt W1 B-frags (frees 32 f32 regs) ----
    half8_t bW1[2][2];
#pragma unroll
    for (int u = 0; u < 2; u++)
#pragma unroll
        for (int kt = 0; kt < 2; kt++)
            bW1[u][kt] = cvt8(w1a[u][kt], w1b[u][kt]);

    // ---- Layer 1 MFMA: kt0 with held frags, kt1 converted on arrival ----
    f32x4 acc[4][2];
#pragma unroll
    for (int mt = 0; mt < 4; mt++)
#pragma unroll
        for (int u = 0; u < 2; u++)
#pragma unroll
            for (int r = 0; r < 4; r++) acc[mt][u][r] = 0.0f;

#pragma unroll
    for (int mt = 0; mt < 4; mt++) {
        acc[mt][0] = __builtin_amdgcn_mfma_f32_16x16x32_f16(aft[mt], bW1[0][0], acc[mt][0], 0, 0, 0);
        acc[mt][1] = __builtin_amdgcn_mfma_f32_16x16x32_f16(aft[mt], bW1[1][0], acc[mt][1], 0, 0, 0);
    }
#pragma unroll
    for (int mt = 0; mt < 4; mt++) {
        half8_t a = cvt8(xa1[mt], xb1[mt]);
        acc[mt][0] = __builtin_amdgcn_mfma_f32_16x16x32_f16(a, bW1[0][1], acc[mt][0], 0, 0, 0);
        acc[mt][1] = __builtin_amdgcn_mfma_f32_16x16x32_f16(a, bW1[1][1], acc[mt][1], 0, 0, 0);
    }

    // ---- h = relu(acc + b1) -> LDS as fp16 (row=16mt+4lq+r, col=16u+l15) ----
#pragma unroll
    for (int mt = 0; mt < 4; mt++)
#pragma unroll
        for (int r = 0; r < 4; r++) {
            int row = 16 * mt + 4 * lq + r;
            hb16[row * HST + l15]      = (__fp16)fmaxf(acc[mt][0][r] + bias0, 0.0f);
            hb16[row * HST + 16 + l15] = (__fp16)fmaxf(acc[mt][1][r] + bias1, 0.0f);
        }
    WAVE_LDS_FENCE();

    // ---- E_raw = h @ W2^T via MFMA; A-frag read directly as half8 (b128) ----
    half8_t bW2 = cvt8(w2a, w2b);
    f32x4 eacc[4];
#pragma unroll
    for (int mt = 0; mt < 4; mt++) {
#pragma unroll
        for (int r = 0; r < 4; r++) eacc[mt][r] = 0.0f;
        half8_t a = *reinterpret_cast<const half8_t*>(hb16 + (16 * mt + l15) * HST + lq * 8);
        eacc[mt] = __builtin_amdgcn_mfma_f32_16x16x32_f16(a, bW2, eacc[mt], 0, 0, 0);
    }

    // C layout -> row-major transpose into the DISJOINT e-buffer (no fence needed before write)
    if (l15 < 4) {
#pragma unroll
        for (int mt = 0; mt < 4; mt++)
#pragma unroll
            for (int r = 0; r < 4; r++)
                eb[(16 * mt + 4 * lq + r) * EST + l15] = eacc[mt][r];
    }
    WAVE_LDS_FENCE();

    float e[4];
    {
        const float2* ep = reinterpret_cast<const float2*>(eb + lane * EST);
        float2 v0 = ep[0], v1 = ep[1];
        e[0] = fast_tanh(v0.x + b2[0]);
        e[1] = fast_tanh(v0.y + b2[1]);
        e[2] = fast_tanh(v1.x + b2[2]);
        e[3] = fast_tanh(v1.y + b2[3]);
    }

    // ---- quantum circuit ----
    float qf[4];
    {
        // Initial 4 RY gates on |0000>: tensor-product construction
        float sn[4], cs[4];
#pragma unroll
        for (int w = 0; w < 4; w++) __sincosf(0.5f * e[w], &sn[w], &cs[w]);
        float t01[4] = { cs[0]*cs[1], cs[0]*sn[1], sn[0]*cs[1], sn[0]*sn[1] };
        float t23[4] = { cs[2]*cs[3], cs[2]*sn[3], sn[2]*cs[3], sn[2]*sn[3] };
        float psi[16];
#pragma unroll
        for (int i = 0; i < 16; i++) psi[i] = t01[i >> 2] * t23[i & 3];

#pragma unroll
        for (int layer = 0; layer < 2; layer++) {
            cnot_gate<8, 4>(psi);
            cnot_gate<4, 2>(psi);
            cnot_gate<2, 1>(psi);
            cnot_gate<1, 8>(psi);
            ry_gate<8>(psi, qpc[layer * 4 + 0], qps[layer * 4 + 0]);
            ry_gate<4>(psi, qpc[layer * 4 + 1], qps[layer * 4 + 1]);
            ry_gate<2>(psi, qpc[layer * 4 + 2], qps[layer * 4 + 2]);
            ry_gate<1>(psi, qpc[layer * 4 + 3], qps[layer * 4 + 3]);
        }

        // Walsh-tree measurement
        float p_[16];
#pragma unroll
        for (int i = 0; i < 16; i++) p_[i] = psi[i] * psi[i];
        float d0 = p_[0] - p_[8],  d1 = p_[1] - p_[9];
        float d2 = p_[2] - p_[10], d3 = p_[3] - p_[11];
        float d4 = p_[4] - p_[12], d5 = p_[5] - p_[13];
        float d6 = p_[6] - p_[14], d7 = p_[7] - p_[15];
        qf[0] = ((d0 + d1) + (d2 + d3)) + ((d4 + d5) + (d6 + d7));
        float s0 = p_[0] + p_[8],  s1 = p_[1] + p_[9];
        float s2 = p_[2] + p_[10], s3 = p_[3] + p_[11];
        float s4 = p_[4] + p_[12], s5 = p_[5] + p_[13];
        float s6 = p_[6] + p_[14], s7 = p_[7] + p_[15];
        qf[1] = ((s0 - s4) + (s1 - s5)) + ((s2 - s6) + (s3 - s7));
        float u0 = s0 + s4, u1 = s1 + s5, u2 = s2 + s6, u3 = s3 + s7;
        qf[2] = (u0 - u2) + (u1 - u3);
        qf[3] = (u0 + u2) - (u1 + u3);
    }

    // ---- H1 layer (K=4, per-thread f32; H1/c1 are uniform s_loads) ----
    float h2v[32];
#pragma unroll
    for (int j = 0; j < 32; j++) {
        float a = c1[j];
        a = fmaf(qf[0], H1[j * 4 + 0], a);
        a = fmaf(qf[1], H1[j * 4 + 1], a);
        a = fmaf(qf[2], H1[j * 4 + 2], a);
        a = fmaf(qf[3], H1[j * 4 + 3], a);
        h2v[j] = fmaxf(a, 0.0f);
    }

    // ---- h2 -> LDS as fp16 (same region as h; h reads were drained at the e-fence) ----
    {
        uint2* wp = reinterpret_cast<uint2*>(hb16 + (size_t)lane * HST);
#pragma unroll
        for (int j = 0; j < 8; j++) {
            fp16x2 q0 = __builtin_amdgcn_cvt_pkrtz(h2v[4 * j],     h2v[4 * j + 1]);
            fp16x2 q1 = __builtin_amdgcn_cvt_pkrtz(h2v[4 * j + 2], h2v[4 * j + 3]);
            wp[j] = make_uint2(__builtin_bit_cast(unsigned int, q0),
                               __builtin_bit_cast(unsigned int, q1));
        }
    }
    WAVE_LDS_FENCE();

    // ---- H2 layer via MFMA: B preloaded in prologue; A-frag read as half8 ----
    half8_t bH2 = cvt8(h2wa, h2wb);
    f32x4 acc2[4];
#pragma unroll
    for (int mt = 0; mt < 4; mt++) {
#pragma unroll
        for (int r = 0; r < 4; r++) acc2[mt][r] = 0.0f;
        half8_t a = *reinterpret_cast<const half8_t*>(hb16 + (16 * mt + l15) * HST + lq * 8);
        acc2[mt] = __builtin_amdgcn_mfma_f32_16x16x32_f16(a, bH2, acc2[mt], 0, 0, 0);
    }

    // ---- epilogue ----
#pragma unroll
    for (int mt = 0; mt < 4; mt++)
#pragma unroll
        for (int r = 0; r < 4; r++) {
            int row = rowBase + 16 * mt + 4 * lq + r;
            out[(size_t)row * 16 + l15] = fast_tanh(acc2[mt][r] + cc);
        }
}

extern "C" void kernel_launch(void* const* d_in, const int* in_sizes, int n_in,
                              void* d_out, int out_size, void* d_ws, size_t ws_size,
                              hipStream_t stream) {
    const float* state = (const float*)d_in[0];
    const float* W1    = (const float*)d_in[1];
    const float* b1    = (const float*)d_in[2];
    const float* W2    = (const float*)d_in[3];
    const float* b2    = (const float*)d_in[4];
    const float* qp    = (const float*)d_in[5];
    const float* H1    = (const float*)d_in[6];
    const float* c1    = (const float*)d_in[7];
    const float* H2    = (const float*)d_in[8];
    const float* c2    = (const float*)d_in[9];
    float* out = (float*)d_out;

    const int blocks = BATCH / TPB;   // 1024
    qnet_kernel<<<blocks, TPB, 0, stream>>>(state, W1, b1, W2, b2, qp,
                                            H1, c1, H2, c2, out);
}

// Round 6
// 119.963 us; speedup vs baseline: 1.0446x; 1.0446x over previous
//
#include <hip/hip_runtime.h>
#include <hip/hip_bf16.h>

#define TPB 256
#define BATCH 262144
#define S 34   // LDS row stride in dwords (even -> 8B rows, <=2-way bank aliasing)

typedef __fp16   fp16x2  __attribute__((ext_vector_type(2)));   // cvt_pkrtz result type
typedef _Float16 half8_t __attribute__((ext_vector_type(8)));
typedef float    f32x4   __attribute__((ext_vector_type(4)));

// Intra-wave LDS fence: waits for this wave's DS ops; LDS slices are
// per-wave so no block-wide __syncthreads is needed (saves 3 barriers).
#define WAVE_LDS_FENCE() asm volatile("s_waitcnt lgkmcnt(0)" ::: "memory")

__device__ __forceinline__ float fast_tanh(float x) {
    float ax = fabsf(x);
    float e  = __expf(-2.0f * ax);
    float t  = (1.0f - e) * __builtin_amdgcn_rcpf(1.0f + e);
    return copysignf(t, x);
}

template <int MASK>
__device__ __forceinline__ void ry_gate(float* psi, float c, float s) {
#pragma unroll
    for (int i = 0; i < 16; i++) {
        if (!(i & MASK)) {
            float a = psi[i], b = psi[i | MASK];
            psi[i]        = c * a - s * b;
            psi[i | MASK] = s * a + c * b;
        }
    }
}

template <int CM, int TM>
__device__ __forceinline__ void cnot_gate(float* psi) {
#pragma unroll
    for (int i = 0; i < 16; i++) {
        if ((i & CM) && !(i & TM)) {
            float t = psi[i];
            psi[i] = psi[i | TM];
            psi[i | TM] = t;
        }
    }
}

__device__ __forceinline__ half8_t cvt8(float4 a, float4 b) {
    fp16x2 p0 = __builtin_amdgcn_cvt_pkrtz(a.x, a.y);
    fp16x2 p1 = __builtin_amdgcn_cvt_pkrtz(a.z, a.w);
    fp16x2 p2 = __builtin_amdgcn_cvt_pkrtz(b.x, b.y);
    fp16x2 p3 = __builtin_amdgcn_cvt_pkrtz(b.z, b.w);
    half8_t r;
    r[0] = (_Float16)p0[0]; r[1] = (_Float16)p0[1];
    r[2] = (_Float16)p1[0]; r[3] = (_Float16)p1[1];
    r[4] = (_Float16)p2[0]; r[5] = (_Float16)p2[1];
    r[6] = (_Float16)p3[0]; r[7] = (_Float16)p3[1];
    return r;
}

__global__ __launch_bounds__(TPB, 4) void qnet_kernel(
    const float* __restrict__ state,
    const float* __restrict__ W1, const float* __restrict__ b1,
    const float* __restrict__ W2, const float* __restrict__ b2,
    const float* __restrict__ qp,
    const float* __restrict__ H1, const float* __restrict__ c1,
    const float* __restrict__ H2, const float* __restrict__ c2,
    float* __restrict__ out)
{
    __shared__ float sh[4 * 64 * S];   // one 64xS slice per wave

    const int tid  = threadIdx.x;
    const int lane = tid & 63;
    const int wv   = tid >> 6;
    const int l15  = lane & 15;
    const int lq   = lane >> 4;
    const int rowBase = blockIdx.x * TPB + wv * 64;
    float* hb = sh + wv * 64 * S;

    // ---- PREFETCH: issue all 8 state loads first (A fragments) ----
    float4 xa[4][2], xb[4][2];   // [mt][kt]
#pragma unroll
    for (int mt = 0; mt < 4; mt++) {
        const float* p0 = state + (size_t)(rowBase + 16 * mt + l15) * 64 + lq * 8;
#pragma unroll
        for (int kt = 0; kt < 2; kt++) {
            xa[mt][kt] = *(const float4*)(p0 + 32 * kt);
            xb[mt][kt] = *(const float4*)(p0 + 32 * kt + 4);
        }
    }

    // ---- B-fragments of W1 (B[k][n] = W1[n*64+k]) ----
    half8_t bW1[2][2];
#pragma unroll
    for (int u = 0; u < 2; u++)
#pragma unroll
        for (int kt = 0; kt < 2; kt++) {
            const float* p = W1 + (16 * u + l15) * 64 + 32 * kt + lq * 8;
            bW1[u][kt] = cvt8(*(const float4*)p, *(const float4*)(p + 4));
        }
    const float bias0 = b1[l15];
    const float bias1 = b1[16 + l15];

    // ---- Layer 1 via MFMA ----
    f32x4 acc[4][2];
#pragma unroll
    for (int mt = 0; mt < 4; mt++)
#pragma unroll
        for (int u = 0; u < 2; u++)
#pragma unroll
            for (int r = 0; r < 4; r++) acc[mt][u][r] = 0.0f;

#pragma unroll
    for (int kt = 0; kt < 2; kt++) {
#pragma unroll
        for (int mt = 0; mt < 4; mt++) {
            half8_t a = cvt8(xa[mt][kt], xb[mt][kt]);
            acc[mt][0] = __builtin_amdgcn_mfma_f32_16x16x32_f16(a, bW1[0][kt], acc[mt][0], 0, 0, 0);
            acc[mt][1] = __builtin_amdgcn_mfma_f32_16x16x32_f16(a, bW1[1][kt], acc[mt][1], 0, 0, 0);
        }
    }

    // ---- h = relu(acc + b1) -> LDS (C layout: row=16mt+4lq+r, col=16u+l15) ----
#pragma unroll
    for (int mt = 0; mt < 4; mt++)
#pragma unroll
        for (int r = 0; r < 4; r++) {
            int row = 16 * mt + 4 * lq + r;
            hb[row * S + l15]      = fmaxf(acc[mt][0][r] + bias0, 0.0f);
            hb[row * S + 16 + l15] = fmaxf(acc[mt][1][r] + bias1, 0.0f);
        }
    WAVE_LDS_FENCE();

    // ---- per-thread middle: my row = lane ----
    float h[32];
    {
        const float2* hr = reinterpret_cast<const float2*>(hb + lane * S);
#pragma unroll
        for (int j = 0; j < 16; j++) { float2 v = hr[j]; h[2 * j] = v.x; h[2 * j + 1] = v.y; }
    }

    float e[4];
#pragma unroll
    for (int w = 0; w < 4; w++) {
        float a = b2[w];
#pragma unroll
        for (int k = 0; k < 32; k++) a = fmaf(h[k], W2[w * 32 + k], a);
        e[w] = fast_tanh(a);
    }

    float qf[4];
    {
        float psi[16];
#pragma unroll
        for (int i = 0; i < 16; i++) psi[i] = 0.0f;
        psi[0] = 1.0f;

        float s, c;
        __sincosf(0.5f * e[0], &s, &c); ry_gate<8>(psi, c, s);
        __sincosf(0.5f * e[1], &s, &c); ry_gate<4>(psi, c, s);
        __sincosf(0.5f * e[2], &s, &c); ry_gate<2>(psi, c, s);
        __sincosf(0.5f * e[3], &s, &c); ry_gate<1>(psi, c, s);

#pragma unroll
        for (int layer = 0; layer < 2; layer++) {
            cnot_gate<8, 4>(psi);
            cnot_gate<4, 2>(psi);
            cnot_gate<2, 1>(psi);
            cnot_gate<1, 8>(psi);
#pragma unroll
            for (int i = 0; i < 4; i++) {
                float s2, c2v;
                __sincosf(0.5f * qp[layer * 4 + i], &s2, &c2v);
                if (i == 0) ry_gate<8>(psi, c2v, s2);
                if (i == 1) ry_gate<4>(psi, c2v, s2);
                if (i == 2) ry_gate<2>(psi, c2v, s2);
                if (i == 3) ry_gate<1>(psi, c2v, s2);
            }
        }

        float p[16];
#pragma unroll
        for (int i = 0; i < 16; i++) p[i] = psi[i] * psi[i];
#pragma unroll
        for (int w = 0; w < 4; w++) {
            const int m = 8 >> w;
            float z = 0.0f;
#pragma unroll
            for (int i = 0; i < 16; i++) z += (i & m) ? -p[i] : p[i];
            qf[w] = z;
        }
    }

    float h2[32];
#pragma unroll
    for (int j = 0; j < 32; j++) {
        float a = c1[j];
        a = fmaf(qf[0], H1[j * 4 + 0], a);
        a = fmaf(qf[1], H1[j * 4 + 1], a);
        a = fmaf(qf[2], H1[j * 4 + 2], a);
        a = fmaf(qf[3], H1[j * 4 + 3], a);
        h2[j] = fmaxf(a, 0.0f);
    }

    WAVE_LDS_FENCE();   // all h reads done; reuse buffer for h2
    {
        float2* hw = reinterpret_cast<float2*>(hb + lane * S);
#pragma unroll
        for (int j = 0; j < 16; j++) hw[j] = make_float2(h2[2 * j], h2[2 * j + 1]);
    }
    WAVE_LDS_FENCE();

    // ---- H2 layer via MFMA: B[k][n] = H2[n*32+k], N=16 ----
    half8_t bH2;
    {
        const float* p = H2 + l15 * 32 + lq * 8;
        bH2 = cvt8(*(const float4*)p, *(const float4*)(p + 4));
    }

    f32x4 acc2[4];
#pragma unroll
    for (int mt = 0; mt < 4; mt++)
#pragma unroll
        for (int r = 0; r < 4; r++) acc2[mt][r] = 0.0f;

#pragma unroll
    for (int mt = 0; mt < 4; mt++) {
        const float2* q = reinterpret_cast<const float2*>(hb + (16 * mt + l15) * S + lq * 8);
        float2 a0 = q[0], a1 = q[1], a2 = q[2], a3 = q[3];
        half8_t a = cvt8(make_float4(a0.x, a0.y, a1.x, a1.y),
                         make_float4(a2.x, a2.y, a3.x, a3.y));
        acc2[mt] = __builtin_amdgcn_mfma_f32_16x16x32_f16(a, bH2, acc2[mt], 0, 0, 0);
    }

    // ---- epilogue ----
    const float cc = c2[l15];
#pragma unroll
    for (int mt = 0; mt < 4; mt++)
#pragma unroll
        for (int r = 0; r < 4; r++) {
            int row = rowBase + 16 * mt + 4 * lq + r;
            out[(size_t)row * 16 + l15] = fast_tanh(acc2[mt][r] + cc);
        }
}

extern "C" void kernel_launch(void* const* d_in, const int* in_sizes, int n_in,
                              void* d_out, int out_size, void* d_ws, size_t ws_size,
                              hipStream_t stream) {
    const float* state = (const float*)d_in[0];
    const float* W1    = (const float*)d_in[1];
    const float* b1    = (const float*)d_in[2];
    const float* W2    = (const float*)d_in[3];
    const float* b2    = (const float*)d_in[4];
    const float* qp    = (const float*)d_in[5];
    const float* H1    = (const float*)d_in[6];
    const float* c1    = (const float*)d_in[7];
    const float* H2    = (const float*)d_in[8];
    const float* c2    = (const float*)d_in[9];
    float* out = (float*)d_out;

    const int blocks = BATCH / TPB;   // 1024
    qnet_kernel<<<blocks, TPB, 0, stream>>>(state, W1, b1, W2, b2, qp,
                                            H1, c1, H2, c2, out);
}